// Round 5
// baseline (116.507 us; speedup 1.0000x reference)
//
#include <hip/hip_runtime.h>
#include <hip/hip_fp16.h>

#define XN 16
#define XC 64
#define XT 30
#define XH 64
#define XW 44
#define OUTW 22
#define ATTH 32
#define OUTH 48
#define SLICE (XH*XW)        // 2816
#define OSLICE (OUTH*OUTW)   // 1056

// ws per-n layout (u32 units): f16 MFMA fragments, lane-indexed
#define WS_FX 0                    // [3][64][4]
#define WS_FY (3*64*4)             // 768: [4][64][4]
#define WS_FT (WS_FY + 4*64*4)     // 1792: [2][64][4]
#define WS_N  (WS_FT + 2*64*4)     // 2304 u32 per n

typedef _Float16 f16;
typedef f16 f16x8 __attribute__((ext_vector_type(8)));
typedef float f32x16 __attribute__((ext_vector_type(16)));
typedef float f32x4 __attribute__((ext_vector_type(4)));

__device__ __forceinline__ unsigned int PK(float a, float b) {
    return __builtin_bit_cast(unsigned int, __builtin_amdgcn_cvt_pkrtz(a, b));
}
__device__ __forceinline__ f32x16 MF(uint4 a, uint4 b, f32x16 c) {
    return __builtin_amdgcn_mfma_f32_32x32x16_f16(
        __builtin_bit_cast(f16x8, a), __builtin_bit_cast(f16x8, b), c, 0, 0, 0);
}
__device__ __forceinline__ f32x16 ZF() {
    f32x16 z;
    #pragma unroll
    for (int i = 0; i < 16; ++i) z[i] = 0.f;
    return z;
}

// ---------------- prep: filterbank fragments -> d_ws ----------------
__global__ void prep_kernel(const float* __restrict__ dtp, const float* __restrict__ dxp,
                            const float* __restrict__ dyp, const float* __restrict__ ls2,
                            const float* __restrict__ ldt, const float* __restrict__ ldp,
                            unsigned int* __restrict__ ws)
{
    __shared__ float fx[22][44];
    __shared__ float fy[32][64];
    __shared__ float ft[30][32];
    const int n = blockIdx.x;
    const int r = threadIdx.x;   // 96 threads
    const float dt_ = tanhf(dtp[n]) * 15.f + 15.f;
    const float dx_ = tanhf(dxp[n]) * 22.f + 22.f;
    const float dy_ = tanhf(dyp[n]) * 32.f + 32.f;
    const float inv2s = 1.f / (2.f * expf(ls2[n]));
    const float delta_t = expf(ldt[n]);
    const float delta = expf(ldp[n]);

    if (r < 30) {
        float mu = dt_ + (float)(r - 15) * delta_t;
        float e[30]; float sum = 0.f;
        for (int t = 0; t < 30; ++t) { float d = (float)t - mu; float v = expf(-d*d*inv2s); e[t] = v; sum += v; }
        float inv = 1.f / fmaxf(sum, 1e-8f);
        for (int t = 0; t < 30; ++t) ft[r][t] = e[t] * inv;
        ft[r][30] = 0.f; ft[r][31] = 0.f;
    } else if (r < 52) {
        int a = r - 30;
        float mu = dx_ + (float)(a - 11) * delta;
        float e[44]; float sum = 0.f;
        for (int w = 0; w < 44; ++w) { float d = (float)w - mu; float v = expf(-d*d*inv2s); e[w] = v; sum += v; }
        float inv = 1.f / fmaxf(sum, 1e-8f);
        for (int w = 0; w < 44; ++w) fx[a][w] = e[w] * inv;
    } else if (r < 84) {
        int b = r - 52;
        float mu = dy_ + (float)(b - 16) * delta;
        float e[64]; float sum = 0.f;
        for (int h = 0; h < 64; ++h) { float d = (float)h - mu; float v = expf(-d*d*inv2s); e[h] = v; sum += v; }
        float inv = 1.f / fmaxf(sum, 1e-8f);
        for (int h = 0; h < 64; ++h) fy[b][h] = e[h] * inv;
    }
    __syncthreads();

    if (r < 64) {
        const int al = r & 31, hf = r >> 5;
        unsigned int* wn = ws + n * WS_N;
        // Fx B-frag for MFMA1: col a = al, k = w
        #pragma unroll
        for (int kt = 0; kt < 3; ++kt) {
            int w0 = kt*16 + 8*hf;
            float v[8];
            #pragma unroll
            for (int i = 0; i < 8; ++i) { int w = w0 + i; v[i] = (al < 22 && w < 44) ? fx[al][w] : 0.f; }
            #pragma unroll
            for (int j = 0; j < 4; ++j) {
                unsigned int lo = __half_as_ushort(__float2half_rn(v[2*j]));
                unsigned int hi = __half_as_ushort(__float2half_rn(v[2*j+1]));
                wn[WS_FX + (kt*64 + r)*4 + j] = lo | (hi << 16);
            }
        }
        // Fy A-frag for MFMA2: row b = al, k = h
        #pragma unroll
        for (int kt = 0; kt < 4; ++kt) {
            int h0 = kt*16 + 8*hf;
            float v[8];
            #pragma unroll
            for (int i = 0; i < 8; ++i) v[i] = fy[al][h0 + i];
            #pragma unroll
            for (int j = 0; j < 4; ++j) {
                unsigned int lo = __half_as_ushort(__float2half_rn(v[2*j]));
                unsigned int hi = __half_as_ushort(__float2half_rn(v[2*j+1]));
                wn[WS_FY + (kt*64 + r)*4 + j] = lo | (hi << 16);
            }
        }
        // Ft A-frag for MFMA3: row s = al, k = t
        #pragma unroll
        for (int kt = 0; kt < 2; ++kt) {
            int t0 = kt*16 + 8*hf;
            float v[8];
            #pragma unroll
            for (int i = 0; i < 8; ++i) v[i] = (al < 30) ? ft[al][t0 + i] : 0.f;
            #pragma unroll
            for (int j = 0; j < 4; ++j) {
                unsigned int lo = __half_as_ushort(__float2half_rn(v[2*j]));
                unsigned int hi = __half_as_ushort(__float2half_rn(v[2*j+1]));
                wn[WS_FT + (kt*64 + r)*4 + j] = lo | (hi << 16);
            }
        }
    }
}

// ---------------- main kernel: one block = one (n,c) ----------------
__global__ __launch_bounds__(256, 3) void glimpse_kernel(
    const float* __restrict__ x, const unsigned int* __restrict__ ws,
    const float* __restrict__ p_lg, float* __restrict__ out)
{
    const int tid = threadIdx.x;
    const int n = blockIdx.x >> 6, c = blockIdx.x & 63;
    const int wv = tid >> 6, l = tid & 63;
    const int al = l & 31, hf = l >> 5;

    __shared__ unsigned int a2t[704*17];     // [ba][17 u32] = [ba][34 f16 t-slots]

    // zero the t=30..33 pad columns (disjoint from hop2's t<30 writes)
    for (int r = tid; r < 704; r += 256) { a2t[r*17 + 15] = 0u; a2t[r*17 + 16] = 0u; }

    // zero-pad output rows (h<8, h>=40), nontemporal
    const size_t obase = (size_t)(n*XC + c) * (XT*OSLICE);
    {
        f32x4 z4 = {0.f, 0.f, 0.f, 0.f};
        f32x4* out4 = (f32x4*)(out + obase);
        #pragma unroll
        for (int k2 = 0; k2 < 11; ++k2) {
            int idx = tid + k2*256;
            if (idx < 2640) {
                int s = idx / 88;
                int rr = idx - s*88;
                int j = (rr < 44) ? rr : (rr + 176);
                __builtin_nontemporal_store(z4, out4 + s*264 + j);
            }
        }
    }

    // preload filter fragments
    const unsigned int* wn = ws + n * WS_N;
    uint4 fxf[3], fyf[4], ftf[2];
    #pragma unroll
    for (int kt = 0; kt < 3; ++kt) fxf[kt] = *(const uint4*)(wn + WS_FX + (kt*64 + l)*4);
    #pragma unroll
    for (int kt = 0; kt < 4; ++kt) fyf[kt] = *(const uint4*)(wn + WS_FY + (kt*64 + l)*4);
    #pragma unroll
    for (int kt = 0; kt < 2; ++kt) ftf[kt] = *(const uint4*)(wn + WS_FT + (kt*64 + l)*4);

    const float gamma = 1.f / (1.f + expf(-p_lg[n]));

    unsigned short* a2t16 = (unsigned short*)a2t;
    const float* xc = x + (size_t)(n*XC + c) * (XT*SLICE);

    // waves own disjoint t's: no barriers in this loop
    #pragma unroll 1
    for (int t = wv; t < XT; t += 4) {
        const float* xs = xc + (size_t)t * SLICE;
        const float* rb0 = xs + al*44;
        const float* rb1 = xs + (32 + al)*44;
        // ---- issue all 12 x loads up front
        float4 A0a = *(const float4*)(rb0 + 8*hf);
        float4 A1a = *(const float4*)(rb0 + 8*hf + 4);
        float4 B0a = *(const float4*)(rb0 + 16 + 8*hf);
        float4 B1a = *(const float4*)(rb0 + 16 + 8*hf + 4);
        float4 C0a = *(const float4*)(rb0 + 32 + 8*hf);
        float4 C1a = (hf == 0) ? *(const float4*)(rb0 + 36) : make_float4(0.f,0.f,0.f,0.f);
        float4 A0b = *(const float4*)(rb1 + 8*hf);
        float4 A1b = *(const float4*)(rb1 + 8*hf + 4);
        float4 B0b = *(const float4*)(rb1 + 16 + 8*hf);
        float4 B1b = *(const float4*)(rb1 + 16 + 8*hf + 4);
        float4 C0b = *(const float4*)(rb1 + 32 + 8*hf);
        float4 C1b = (hf == 0) ? *(const float4*)(rb1 + 36) : make_float4(0.f,0.f,0.f,0.f);

        f32x16 D0 = ZF(), D1m = ZF(), D2 = ZF();
        // MFMA1: A1[h][a] = sum_w x[h][w] * FxT[w][a]
        {
            uint4 u0 = make_uint4(PK(A0a.x,A0a.y), PK(A0a.z,A0a.w), PK(A1a.x,A1a.y), PK(A1a.z,A1a.w));
            uint4 u1 = make_uint4(PK(B0a.x,B0a.y), PK(B0a.z,B0a.w), PK(B1a.x,B1a.y), PK(B1a.z,B1a.w));
            uint4 u2 = make_uint4(PK(C0a.x,C0a.y), PK(C0a.z,C0a.w), PK(C1a.x,C1a.y), PK(C1a.z,C1a.w));
            D0 = MF(u0, fxf[0], D0); D0 = MF(u1, fxf[1], D0); D0 = MF(u2, fxf[2], D0);
        }
        {
            uint4 u0 = make_uint4(PK(A0b.x,A0b.y), PK(A0b.z,A0b.w), PK(A1b.x,A1b.y), PK(A1b.z,A1b.w));
            uint4 u1 = make_uint4(PK(B0b.x,B0b.y), PK(B0b.z,B0b.w), PK(B1b.x,B1b.y), PK(B1b.z,B1b.w));
            uint4 u2 = make_uint4(PK(C0b.x,C0b.y), PK(C0b.z,C0b.w), PK(C1b.x,C1b.y), PK(C1b.z,C1b.w));
            D1m = MF(u0, fxf[0], D1m); D1m = MF(u1, fxf[1], D1m); D1m = MF(u2, fxf[2], D1m);
        }

        // ---- hop1 in-register: D (col a, rows h spread over lane halves)
        //      -> MFMA2 B-frags via half-wave exchange. frag(kt) uses pack-group
        //      g = 2*ktloc + hf from BOTH halves.
        #pragma unroll
        for (int half = 0; half < 2; ++half) {
            const f32x16& D = half ? D1m : D0;
            unsigned int w0g[4], w1g[4];
            #pragma unroll
            for (int g = 0; g < 4; ++g) {
                w0g[g] = PK(D[4*g],   D[4*g+1]);
                w1g[g] = PK(D[4*g+2], D[4*g+3]);
            }
            #pragma unroll
            for (int ktl = 0; ktl < 2; ++ktl) {
                const int gA = 2*ktl, gB = 2*ktl + 1;
                unsigned int own0 = hf ? w0g[gB] : w0g[gA];
                unsigned int own1 = hf ? w1g[gB] : w1g[gA];
                unsigned int snd0 = hf ? w0g[gA] : w0g[gB];
                unsigned int snd1 = hf ? w1g[gA] : w1g[gB];
                unsigned int rcv0 = (unsigned int)__shfl_xor((int)snd0, 32, 64);
                unsigned int rcv1 = (unsigned int)__shfl_xor((int)snd1, 32, 64);
                uint4 frag;
                frag.x = hf ? rcv0 : own0;
                frag.y = hf ? rcv1 : own1;
                frag.z = hf ? own0 : rcv0;
                frag.w = hf ? own1 : rcv1;
                D2 = MF(fyf[half*2 + ktl], frag, D2);
            }
        }

        // hop2: D2 (col a, rows b) -> a2t[b*22+a][t] f16
        if (al < 22) {
            #pragma unroll
            for (int q = 0; q < 16; ++q) {
                int b = (q & 3) + 8*(q >> 2) + 4*hf;
                unsigned short hv = __builtin_bit_cast(unsigned short, (_Float16)D2[q]);
                a2t16[(b*22 + al)*34 + t] = hv;
            }
        }
    }
    __syncthreads();

    // MFMA3: G[s][ba] = sum_t Ft[s][t] * A2t[ba][t]
    #pragma unroll 2
    for (int nt = wv; nt < 22; nt += 4) {
        int ba = nt*32 + al;
        f32x16 D3 = ZF();
        #pragma unroll
        for (int kt = 0; kt < 2; ++kt) {
            int base = ba*17 + kt*8 + 4*hf;
            uint4 bw;
            bw.x = a2t[base]; bw.y = a2t[base+1]; bw.z = a2t[base+2]; bw.w = a2t[base+3];
            D3 = MF(ftf[kt], bw, D3);
        }
        float* ob = out + obase + 176 + ba;
        #pragma unroll
        for (int q = 0; q < 16; ++q) {
            int s = (q & 3) + 8*(q >> 2) + 4*hf;
            if (s < XT) __builtin_nontemporal_store(gamma * D3[q], ob + s*OSLICE);
        }
    }
}

extern "C" void kernel_launch(void* const* d_in, const int* in_sizes, int n_in,
                              void* d_out, int out_size, void* d_ws, size_t ws_size,
                              hipStream_t stream) {
    const float* x   = (const float*)d_in[0];
    const float* dt  = (const float*)d_in[1];
    const float* dx  = (const float*)d_in[2];
    const float* dy  = (const float*)d_in[3];
    const float* ls2 = (const float*)d_in[4];
    const float* ldt = (const float*)d_in[5];
    const float* ld  = (const float*)d_in[6];
    const float* lg  = (const float*)d_in[7];
    float* out = (float*)d_out;
    unsigned int* ws = (unsigned int*)d_ws;   // 16 * 2304 * 4B = 147 KB

    prep_kernel<<<dim3(XN), dim3(96), 0, stream>>>(dt, dx, dy, ls2, ldt, ld, ws);
    glimpse_kernel<<<dim3(XN * XC), dim3(256), 0, stream>>>(x, ws, lg, out);
}

// Round 6
// 113.142 us; speedup vs baseline: 1.0297x; 1.0297x over previous
//
#include <hip/hip_runtime.h>
#include <hip/hip_fp16.h>

#define XN 16
#define XC 64
#define XT 30
#define XH 64
#define XW 44
#define OUTW 22
#define ATTH 32
#define OUTH 48
#define SLICE (XH*XW)        // 2816
#define OSLICE (OUTH*OUTW)   // 1056

// ws per-n layout (u32 units): f16 MFMA fragments, lane-indexed
#define WS_FX 0                    // [3][64][4]
#define WS_FY (3*64*4)             // 768: [4][64][4]
#define WS_FT (WS_FY + 4*64*4)     // 1792: [2][64][4]
#define WS_N  (WS_FT + 2*64*4)     // 2304 u32 per n

typedef _Float16 f16;
typedef f16 f16x8 __attribute__((ext_vector_type(8)));
typedef float f32x16 __attribute__((ext_vector_type(16)));
typedef float f32x4 __attribute__((ext_vector_type(4)));

__device__ __forceinline__ unsigned int PK(float a, float b) {
    return __builtin_bit_cast(unsigned int, __builtin_amdgcn_cvt_pkrtz(a, b));
}
__device__ __forceinline__ f32x16 MF(uint4 a, uint4 b, f32x16 c) {
    return __builtin_amdgcn_mfma_f32_32x32x16_f16(
        __builtin_bit_cast(f16x8, a), __builtin_bit_cast(f16x8, b), c, 0, 0, 0);
}
__device__ __forceinline__ f32x16 ZF() {
    f32x16 z;
    #pragma unroll
    for (int i = 0; i < 16; ++i) z[i] = 0.f;
    return z;
}

// ---------------- prep: filterbank fragments -> d_ws ----------------
__global__ void prep_kernel(const float* __restrict__ dtp, const float* __restrict__ dxp,
                            const float* __restrict__ dyp, const float* __restrict__ ls2,
                            const float* __restrict__ ldt, const float* __restrict__ ldp,
                            unsigned int* __restrict__ ws)
{
    __shared__ float fx[22][44];
    __shared__ float fy[32][64];
    __shared__ float ft[30][32];
    const int n = blockIdx.x;
    const int r = threadIdx.x;   // 96 threads
    const float dt_ = tanhf(dtp[n]) * 15.f + 15.f;
    const float dx_ = tanhf(dxp[n]) * 22.f + 22.f;
    const float dy_ = tanhf(dyp[n]) * 32.f + 32.f;
    const float inv2s = 1.f / (2.f * expf(ls2[n]));
    const float delta_t = expf(ldt[n]);
    const float delta = expf(ldp[n]);

    if (r < 30) {
        float mu = dt_ + (float)(r - 15) * delta_t;
        float e[30]; float sum = 0.f;
        for (int t = 0; t < 30; ++t) { float d = (float)t - mu; float v = expf(-d*d*inv2s); e[t] = v; sum += v; }
        float inv = 1.f / fmaxf(sum, 1e-8f);
        for (int t = 0; t < 30; ++t) ft[r][t] = e[t] * inv;
        ft[r][30] = 0.f; ft[r][31] = 0.f;
    } else if (r < 52) {
        int a = r - 30;
        float mu = dx_ + (float)(a - 11) * delta;
        float e[44]; float sum = 0.f;
        for (int w = 0; w < 44; ++w) { float d = (float)w - mu; float v = expf(-d*d*inv2s); e[w] = v; sum += v; }
        float inv = 1.f / fmaxf(sum, 1e-8f);
        for (int w = 0; w < 44; ++w) fx[a][w] = e[w] * inv;
    } else if (r < 84) {
        int b = r - 52;
        float mu = dy_ + (float)(b - 16) * delta;
        float e[64]; float sum = 0.f;
        for (int h = 0; h < 64; ++h) { float d = (float)h - mu; float v = expf(-d*d*inv2s); e[h] = v; sum += v; }
        float inv = 1.f / fmaxf(sum, 1e-8f);
        for (int h = 0; h < 64; ++h) fy[b][h] = e[h] * inv;
    }
    __syncthreads();

    if (r < 64) {
        const int al = r & 31, hf = r >> 5;
        unsigned int* wn = ws + n * WS_N;
        // Fx B-frag for MFMA1: col a = al, k = w
        #pragma unroll
        for (int kt = 0; kt < 3; ++kt) {
            int w0 = kt*16 + 8*hf;
            float v[8];
            #pragma unroll
            for (int i = 0; i < 8; ++i) { int w = w0 + i; v[i] = (al < 22 && w < 44) ? fx[al][w] : 0.f; }
            #pragma unroll
            for (int j = 0; j < 4; ++j) {
                unsigned int lo = __half_as_ushort(__float2half_rn(v[2*j]));
                unsigned int hi = __half_as_ushort(__float2half_rn(v[2*j+1]));
                wn[WS_FX + (kt*64 + r)*4 + j] = lo | (hi << 16);
            }
        }
        // Fy A-frag for MFMA2: row b = al, k = h
        #pragma unroll
        for (int kt = 0; kt < 4; ++kt) {
            int h0 = kt*16 + 8*hf;
            float v[8];
            #pragma unroll
            for (int i = 0; i < 8; ++i) v[i] = fy[al][h0 + i];
            #pragma unroll
            for (int j = 0; j < 4; ++j) {
                unsigned int lo = __half_as_ushort(__float2half_rn(v[2*j]));
                unsigned int hi = __half_as_ushort(__float2half_rn(v[2*j+1]));
                wn[WS_FY + (kt*64 + r)*4 + j] = lo | (hi << 16);
            }
        }
        // Ft A-frag for MFMA3: row s = al, k = t
        #pragma unroll
        for (int kt = 0; kt < 2; ++kt) {
            int t0 = kt*16 + 8*hf;
            float v[8];
            #pragma unroll
            for (int i = 0; i < 8; ++i) v[i] = (al < 30) ? ft[al][t0 + i] : 0.f;
            #pragma unroll
            for (int j = 0; j < 4; ++j) {
                unsigned int lo = __half_as_ushort(__float2half_rn(v[2*j]));
                unsigned int hi = __half_as_ushort(__float2half_rn(v[2*j+1]));
                wn[WS_FT + (kt*64 + r)*4 + j] = lo | (hi << 16);
            }
        }
    }
}

// ---------------- main kernel: one block = one (n,c) ----------------
// LDS: per-wave f16 half-slice stage [32 rows][32 u32] XOR-swizzled (4KB x 4 waves)
//      + a2t [704][17 u32]  => 16064 u32 = 64256 B (< 64KB)
__global__ __launch_bounds__(256, 2) void glimpse_kernel(
    const float* __restrict__ x, const unsigned int* __restrict__ ws,
    const float* __restrict__ p_lg, float* __restrict__ out)
{
    const int tid = threadIdx.x;
    const int n = blockIdx.x >> 6, c = blockIdx.x & 63;
    const int wv = tid >> 6, l = tid & 63;
    const int al = l & 31, hf = l >> 5;

    __shared__ unsigned int lds_all[4*1024 + 704*17];
    unsigned int* xst = lds_all + wv * 1024;
    unsigned int* a2t = lds_all + 4096;

    // zero a2t t=30..33 pad columns (disjoint from hop2's t<30 writes)
    for (int r = tid; r < 704; r += 256) { a2t[r*17 + 15] = 0u; a2t[r*17 + 16] = 0u; }
    // zero stage-buffer pad cols (w44..47 => logical block 5, u32 sub 2,3) once
    if (l < 32) {
        int ph = l*32 + ((5 ^ (l & 7)) << 2) + 2;
        xst[ph] = 0u; xst[ph + 1] = 0u;
    }

    // zero-pad output rows (h<8, h>=40), nontemporal
    const size_t obase = (size_t)(n*XC + c) * (XT*OSLICE);
    {
        f32x4 z4 = {0.f, 0.f, 0.f, 0.f};
        f32x4* out4 = (f32x4*)(out + obase);
        #pragma unroll
        for (int k2 = 0; k2 < 11; ++k2) {
            int idx = tid + k2*256;
            if (idx < 2640) {
                int s = idx / 88;
                int rr = idx - s*88;
                int j = (rr < 44) ? rr : (rr + 176);
                __builtin_nontemporal_store(z4, out4 + s*264 + j);
            }
        }
    }

    // preload filter fragments
    const unsigned int* wn = ws + n * WS_N;
    uint4 fxf[3], fyf[4], ftf[2];
    #pragma unroll
    for (int kt = 0; kt < 3; ++kt) fxf[kt] = *(const uint4*)(wn + WS_FX + (kt*64 + l)*4);
    #pragma unroll
    for (int kt = 0; kt < 4; ++kt) fyf[kt] = *(const uint4*)(wn + WS_FY + (kt*64 + l)*4);
    #pragma unroll
    for (int kt = 0; kt < 2; ++kt) ftf[kt] = *(const uint4*)(wn + WS_FT + (kt*64 + l)*4);

    const float gamma = 1.f / (1.f + expf(-p_lg[n]));

    unsigned short* a2t16 = (unsigned short*)a2t;
    const float* xc = x + (size_t)(n*XC + c) * (XT*SLICE);

    // ---- software-pipelined t-loop: coalesced loads issued one iter ahead
    float4 v[11];
    {
        const float4* src = (const float4*)(xc + (size_t)wv * SLICE);
        #pragma unroll
        for (int k = 0; k < 11; ++k) v[k] = src[k*64 + l];
    }

    #pragma unroll 1
    for (int t = wv; t < XT; t += 4) {
        // pack current slice to f16 pairs (frees v for prefetch)
        unsigned int pk[22];
        #pragma unroll
        for (int k = 0; k < 11; ++k) {
            pk[2*k]   = PK(v[k].x, v[k].y);
            pk[2*k+1] = PK(v[k].z, v[k].w);
        }
        // issue next iteration's coalesced loads (fire-and-forget)
        if (t + 4 < XT) {
            const float4* src = (const float4*)(xc + (size_t)(t+4) * SLICE);
            #pragma unroll
            for (int k = 0; k < 11; ++k) v[k] = src[k*64 + l];
        }

        f32x16 D0 = ZF(), D1m = ZF(), D2 = ZF();
        // ---- stage rows 0..31 (phase 1): lane's float4 k -> row r, u32 cols c,c+1
        #pragma unroll
        for (int k = 0; k < 6; ++k) {
            int flat = k*64 + l;
            if (k < 5 || l < 32) {
                int r = flat / 11;
                int m = flat - r*11;
                int ph = (r & 31)*32 + (((m >> 1) ^ (r & 7)) << 2) + ((m & 1) << 1);
                uint2 pr; pr.x = pk[2*k]; pr.y = pk[2*k+1];
                *(uint2*)(xst + ph) = pr;
            }
        }
        // frags mt0 (rows = al): logical 16B block b = kt*2+hf, XOR-swizzled
        {
            uint4 u0 = *(const uint4*)(xst + al*32 + (((0 + hf) ^ (al & 7)) << 2));
            uint4 u1 = *(const uint4*)(xst + al*32 + (((2 + hf) ^ (al & 7)) << 2));
            uint4 u2 = *(const uint4*)(xst + al*32 + (((4 + hf) ^ (al & 7)) << 2));
            D0 = MF(u0, fxf[0], D0); D0 = MF(u1, fxf[1], D0); D0 = MF(u2, fxf[2], D0);
        }
        // ---- stage rows 32..63 (phase 2) into same buffer
        #pragma unroll
        for (int k = 5; k < 11; ++k) {
            int flat = k*64 + l;
            if (k > 5 || l >= 32) {
                int r = flat / 11;
                int m = flat - r*11;
                int ph = (r & 31)*32 + (((m >> 1) ^ (r & 7)) << 2) + ((m & 1) << 1);
                uint2 pr; pr.x = pk[2*k]; pr.y = pk[2*k+1];
                *(uint2*)(xst + ph) = pr;
            }
        }
        // frags mt1
        {
            uint4 u0 = *(const uint4*)(xst + al*32 + (((0 + hf) ^ (al & 7)) << 2));
            uint4 u1 = *(const uint4*)(xst + al*32 + (((2 + hf) ^ (al & 7)) << 2));
            uint4 u2 = *(const uint4*)(xst + al*32 + (((4 + hf) ^ (al & 7)) << 2));
            D1m = MF(u0, fxf[0], D1m); D1m = MF(u1, fxf[1], D1m); D1m = MF(u2, fxf[2], D1m);
        }

        // ---- hop1 in-register: D (col a, rows h spread over lane halves)
        //      -> MFMA2 B-frags via half-wave exchange
        #pragma unroll
        for (int half = 0; half < 2; ++half) {
            const f32x16& D = half ? D1m : D0;
            unsigned int w0g[4], w1g[4];
            #pragma unroll
            for (int g = 0; g < 4; ++g) {
                w0g[g] = PK(D[4*g],   D[4*g+1]);
                w1g[g] = PK(D[4*g+2], D[4*g+3]);
            }
            #pragma unroll
            for (int ktl = 0; ktl < 2; ++ktl) {
                const int gA = 2*ktl, gB = 2*ktl + 1;
                unsigned int own0 = hf ? w0g[gB] : w0g[gA];
                unsigned int own1 = hf ? w1g[gB] : w1g[gA];
                unsigned int snd0 = hf ? w0g[gA] : w0g[gB];
                unsigned int snd1 = hf ? w1g[gA] : w1g[gB];
                unsigned int rcv0 = (unsigned int)__shfl_xor((int)snd0, 32, 64);
                unsigned int rcv1 = (unsigned int)__shfl_xor((int)snd1, 32, 64);
                uint4 frag;
                frag.x = hf ? rcv0 : own0;
                frag.y = hf ? rcv1 : own1;
                frag.z = hf ? own0 : rcv0;
                frag.w = hf ? own1 : rcv1;
                D2 = MF(fyf[half*2 + ktl], frag, D2);
            }
        }

        // hop2: D2 (col a, rows b) -> a2t[b*22+a][t] f16
        if (al < 22) {
            #pragma unroll
            for (int q = 0; q < 16; ++q) {
                int b = (q & 3) + 8*(q >> 2) + 4*hf;
                unsigned short hv = __builtin_bit_cast(unsigned short, (_Float16)D2[q]);
                a2t16[(b*22 + al)*34 + t] = hv;
            }
        }
    }
    __syncthreads();

    // MFMA3: G[s][ba] = sum_t Ft[s][t] * A2t[ba][t]
    #pragma unroll 2
    for (int nt = wv; nt < 22; nt += 4) {
        int ba = nt*32 + al;
        f32x16 D3 = ZF();
        #pragma unroll
        for (int kt = 0; kt < 2; ++kt) {
            int base = ba*17 + kt*8 + 4*hf;
            uint4 bw;
            bw.x = a2t[base]; bw.y = a2t[base+1]; bw.z = a2t[base+2]; bw.w = a2t[base+3];
            D3 = MF(ftf[kt], bw, D3);
        }
        float* ob = out + obase + 176 + ba;
        #pragma unroll
        for (int q = 0; q < 16; ++q) {
            int s = (q & 3) + 8*(q >> 2) + 4*hf;
            if (s < XT) __builtin_nontemporal_store(gamma * D3[q], ob + s*OSLICE);
        }
    }
}

extern "C" void kernel_launch(void* const* d_in, const int* in_sizes, int n_in,
                              void* d_out, int out_size, void* d_ws, size_t ws_size,
                              hipStream_t stream) {
    const float* x   = (const float*)d_in[0];
    const float* dt  = (const float*)d_in[1];
    const float* dx  = (const float*)d_in[2];
    const float* dy  = (const float*)d_in[3];
    const float* ls2 = (const float*)d_in[4];
    const float* ldt = (const float*)d_in[5];
    const float* ld  = (const float*)d_in[6];
    const float* lg  = (const float*)d_in[7];
    float* out = (float*)d_out;
    unsigned int* ws = (unsigned int*)d_ws;   // 16 * 2304 * 4B = 147 KB

    prep_kernel<<<dim3(XN), dim3(96), 0, stream>>>(dt, dx, dy, ls2, ldt, ld, ws);
    glimpse_kernel<<<dim3(XN * XC), dim3(256), 0, stream>>>(x, ws, lg, out);
}

// Round 7
// 110.226 us; speedup vs baseline: 1.0570x; 1.0265x over previous
//
#include <hip/hip_runtime.h>
#include <hip/hip_fp16.h>

#define XN 16
#define XC 64
#define XT 30
#define XH 64
#define XW 44
#define OUTW 22
#define ATTH 32
#define OUTH 48
#define SLICE (XH*XW)        // 2816
#define OSLICE (OUTH*OUTW)   // 1056

// ws per-n layout (u32 units): f16 MFMA fragments, lane-indexed
#define WS_FX 0                    // [3][64][4]
#define WS_FY (3*64*4)             // 768: [4][64][4]
#define WS_FT (WS_FY + 4*64*4)     // 1792: [2][64][4]
#define WS_N  (WS_FT + 2*64*4)     // 2304 u32 per n

typedef _Float16 f16;
typedef f16 f16x8 __attribute__((ext_vector_type(8)));
typedef float f32x16 __attribute__((ext_vector_type(16)));
typedef float f32x4 __attribute__((ext_vector_type(4)));

__device__ __forceinline__ unsigned int PK(float a, float b) {
    return __builtin_bit_cast(unsigned int, __builtin_amdgcn_cvt_pkrtz(a, b));
}
__device__ __forceinline__ f32x16 MF(uint4 a, uint4 b, f32x16 c) {
    return __builtin_amdgcn_mfma_f32_32x32x16_f16(
        __builtin_bit_cast(f16x8, a), __builtin_bit_cast(f16x8, b), c, 0, 0, 0);
}
__device__ __forceinline__ f32x16 ZF() {
    f32x16 z;
    #pragma unroll
    for (int i = 0; i < 16; ++i) z[i] = 0.f;
    return z;
}

// ---------------- prep: filterbank fragments -> d_ws ----------------
__global__ void prep_kernel(const float* __restrict__ dtp, const float* __restrict__ dxp,
                            const float* __restrict__ dyp, const float* __restrict__ ls2,
                            const float* __restrict__ ldt, const float* __restrict__ ldp,
                            unsigned int* __restrict__ ws)
{
    __shared__ float fx[22][44];
    __shared__ float fy[32][64];
    __shared__ float ft[30][32];
    const int n = blockIdx.x;
    const int r = threadIdx.x;   // 96 threads
    const float dt_ = tanhf(dtp[n]) * 15.f + 15.f;
    const float dx_ = tanhf(dxp[n]) * 22.f + 22.f;
    const float dy_ = tanhf(dyp[n]) * 32.f + 32.f;
    const float inv2s = 1.f / (2.f * expf(ls2[n]));
    const float delta_t = expf(ldt[n]);
    const float delta = expf(ldp[n]);

    if (r < 30) {
        float mu = dt_ + (float)(r - 15) * delta_t;
        float e[30]; float sum = 0.f;
        for (int t = 0; t < 30; ++t) { float d = (float)t - mu; float v = expf(-d*d*inv2s); e[t] = v; sum += v; }
        float inv = 1.f / fmaxf(sum, 1e-8f);
        for (int t = 0; t < 30; ++t) ft[r][t] = e[t] * inv;
        ft[r][30] = 0.f; ft[r][31] = 0.f;
    } else if (r < 52) {
        int a = r - 30;
        float mu = dx_ + (float)(a - 11) * delta;
        float e[44]; float sum = 0.f;
        for (int w = 0; w < 44; ++w) { float d = (float)w - mu; float v = expf(-d*d*inv2s); e[w] = v; sum += v; }
        float inv = 1.f / fmaxf(sum, 1e-8f);
        for (int w = 0; w < 44; ++w) fx[a][w] = e[w] * inv;
    } else if (r < 84) {
        int b = r - 52;
        float mu = dy_ + (float)(b - 16) * delta;
        float e[64]; float sum = 0.f;
        for (int h = 0; h < 64; ++h) { float d = (float)h - mu; float v = expf(-d*d*inv2s); e[h] = v; sum += v; }
        float inv = 1.f / fmaxf(sum, 1e-8f);
        for (int h = 0; h < 64; ++h) fy[b][h] = e[h] * inv;
    }
    __syncthreads();

    if (r < 64) {
        const int al = r & 31, hf = r >> 5;
        unsigned int* wn = ws + n * WS_N;
        // Fx B-frag for MFMA1: col a = al, k = w
        #pragma unroll
        for (int kt = 0; kt < 3; ++kt) {
            int w0 = kt*16 + 8*hf;
            float v[8];
            #pragma unroll
            for (int i = 0; i < 8; ++i) { int w = w0 + i; v[i] = (al < 22 && w < 44) ? fx[al][w] : 0.f; }
            #pragma unroll
            for (int j = 0; j < 4; ++j) {
                unsigned int lo = __half_as_ushort(__float2half_rn(v[2*j]));
                unsigned int hi = __half_as_ushort(__float2half_rn(v[2*j+1]));
                wn[WS_FX + (kt*64 + r)*4 + j] = lo | (hi << 16);
            }
        }
        // Fy A-frag for MFMA2: row b = al, k = h
        #pragma unroll
        for (int kt = 0; kt < 4; ++kt) {
            int h0 = kt*16 + 8*hf;
            float v[8];
            #pragma unroll
            for (int i = 0; i < 8; ++i) v[i] = fy[al][h0 + i];
            #pragma unroll
            for (int j = 0; j < 4; ++j) {
                unsigned int lo = __half_as_ushort(__float2half_rn(v[2*j]));
                unsigned int hi = __half_as_ushort(__float2half_rn(v[2*j+1]));
                wn[WS_FY + (kt*64 + r)*4 + j] = lo | (hi << 16);
            }
        }
        // Ft A-frag for MFMA3: row s = al, k = t
        #pragma unroll
        for (int kt = 0; kt < 2; ++kt) {
            int t0 = kt*16 + 8*hf;
            float v[8];
            #pragma unroll
            for (int i = 0; i < 8; ++i) v[i] = (al < 30) ? ft[al][t0 + i] : 0.f;
            #pragma unroll
            for (int j = 0; j < 4; ++j) {
                unsigned int lo = __half_as_ushort(__float2half_rn(v[2*j]));
                unsigned int hi = __half_as_ushort(__float2half_rn(v[2*j+1]));
                wn[WS_FT + (kt*64 + r)*4 + j] = lo | (hi << 16);
            }
        }
    }
}

// ---------------- main kernel: one block = one (n,c), 512 threads ----------------
__global__ __launch_bounds__(512, 2) void glimpse_kernel(
    const float* __restrict__ x, const unsigned int* __restrict__ ws,
    const float* __restrict__ p_lg, float* __restrict__ out)
{
    const int tid = threadIdx.x;
    const int n = blockIdx.x >> 6, c = blockIdx.x & 63;
    const int wv = tid >> 6, l = tid & 63;
    const int al = l & 31, hf = l >> 5;

    __shared__ unsigned int a2t[704*17];     // [ba][17 u32] = [ba][34 f16 t-slots]

    // zero the t=30..33 pad columns (disjoint from hop2's t<30 writes)
    for (int r = tid; r < 704; r += 512) { a2t[r*17 + 15] = 0u; a2t[r*17 + 16] = 0u; }

    // zero-pad output rows (h<8, h>=40), nontemporal
    const size_t obase = (size_t)(n*XC + c) * (XT*OSLICE);
    {
        f32x4 z4 = {0.f, 0.f, 0.f, 0.f};
        f32x4* out4 = (f32x4*)(out + obase);
        #pragma unroll
        for (int k2 = 0; k2 < 6; ++k2) {
            int idx = tid + k2*512;
            if (idx < 2640) {
                int s = idx / 88;
                int rr = idx - s*88;
                int j = (rr < 44) ? rr : (rr + 176);
                __builtin_nontemporal_store(z4, out4 + s*264 + j);
            }
        }
    }

    // preload filter fragments
    const unsigned int* wn = ws + n * WS_N;
    uint4 fxf[3], fyf[4], ftf[2];
    #pragma unroll
    for (int kt = 0; kt < 3; ++kt) fxf[kt] = *(const uint4*)(wn + WS_FX + (kt*64 + l)*4);
    #pragma unroll
    for (int kt = 0; kt < 4; ++kt) fyf[kt] = *(const uint4*)(wn + WS_FY + (kt*64 + l)*4);
    #pragma unroll
    for (int kt = 0; kt < 2; ++kt) ftf[kt] = *(const uint4*)(wn + WS_FT + (kt*64 + l)*4);

    const float gamma = 1.f / (1.f + expf(-p_lg[n]));

    unsigned short* a2t16 = (unsigned short*)a2t;
    const float* xc = x + (size_t)(n*XC + c) * (XT*SLICE);

    // two super-iters; each loads TWO slices' worth (24 dwordx4) before computing
    #pragma unroll 1
    for (int si = 0; si < 2; ++si) {
        const int tA = wv + si*16;
        const int tB = tA + 8;
        const bool doB = (tB < XT);   // wave-uniform

        float4 LA0, LA1, LA2, LA3, LA4, LA5, LA6, LA7, LA8, LA9, LA10, LA11;
        float4 LB0, LB1, LB2, LB3, LB4, LB5, LB6, LB7, LB8, LB9, LB10, LB11;
        {
            const float* rb0 = xc + (size_t)tA * SLICE + al*44;
            const float* rb1 = rb0 + 32*44;
            LA0 = *(const float4*)(rb0 + 8*hf);
            LA1 = *(const float4*)(rb0 + 8*hf + 4);
            LA2 = *(const float4*)(rb0 + 16 + 8*hf);
            LA3 = *(const float4*)(rb0 + 16 + 8*hf + 4);
            LA4 = *(const float4*)(rb0 + 32 + 8*hf);
            LA5 = (hf == 0) ? *(const float4*)(rb0 + 36) : make_float4(0.f,0.f,0.f,0.f);
            LA6 = *(const float4*)(rb1 + 8*hf);
            LA7 = *(const float4*)(rb1 + 8*hf + 4);
            LA8 = *(const float4*)(rb1 + 16 + 8*hf);
            LA9 = *(const float4*)(rb1 + 16 + 8*hf + 4);
            LA10 = *(const float4*)(rb1 + 32 + 8*hf);
            LA11 = (hf == 0) ? *(const float4*)(rb1 + 36) : make_float4(0.f,0.f,0.f,0.f);
        }
        if (doB) {
            const float* rb0 = xc + (size_t)tB * SLICE + al*44;
            const float* rb1 = rb0 + 32*44;
            LB0 = *(const float4*)(rb0 + 8*hf);
            LB1 = *(const float4*)(rb0 + 8*hf + 4);
            LB2 = *(const float4*)(rb0 + 16 + 8*hf);
            LB3 = *(const float4*)(rb0 + 16 + 8*hf + 4);
            LB4 = *(const float4*)(rb0 + 32 + 8*hf);
            LB5 = (hf == 0) ? *(const float4*)(rb0 + 36) : make_float4(0.f,0.f,0.f,0.f);
            LB6 = *(const float4*)(rb1 + 8*hf);
            LB7 = *(const float4*)(rb1 + 8*hf + 4);
            LB8 = *(const float4*)(rb1 + 16 + 8*hf);
            LB9 = *(const float4*)(rb1 + 16 + 8*hf + 4);
            LB10 = *(const float4*)(rb1 + 32 + 8*hf);
            LB11 = (hf == 0) ? *(const float4*)(rb1 + 36) : make_float4(0.f,0.f,0.f,0.f);
        }

        #pragma unroll
        for (int sl = 0; sl < 2; ++sl) {
            if (sl == 1 && !doB) break;
            const int t = sl ? tB : tA;
            f32x16 D0 = ZF(), D1m = ZF(), D2 = ZF();
            {
                float4 a0 = sl ? LB0 : LA0,  a1 = sl ? LB1 : LA1;
                float4 a2 = sl ? LB2 : LA2,  a3 = sl ? LB3 : LA3;
                float4 a4 = sl ? LB4 : LA4,  a5 = sl ? LB5 : LA5;
                uint4 u0 = make_uint4(PK(a0.x,a0.y), PK(a0.z,a0.w), PK(a1.x,a1.y), PK(a1.z,a1.w));
                uint4 u1 = make_uint4(PK(a2.x,a2.y), PK(a2.z,a2.w), PK(a3.x,a3.y), PK(a3.z,a3.w));
                uint4 u2 = make_uint4(PK(a4.x,a4.y), PK(a4.z,a4.w), PK(a5.x,a5.y), PK(a5.z,a5.w));
                D0 = MF(u0, fxf[0], D0); D0 = MF(u1, fxf[1], D0); D0 = MF(u2, fxf[2], D0);
            }
            {
                float4 a0 = sl ? LB6 : LA6,  a1 = sl ? LB7 : LA7;
                float4 a2 = sl ? LB8 : LA8,  a3 = sl ? LB9 : LA9;
                float4 a4 = sl ? LB10 : LA10, a5 = sl ? LB11 : LA11;
                uint4 u0 = make_uint4(PK(a0.x,a0.y), PK(a0.z,a0.w), PK(a1.x,a1.y), PK(a1.z,a1.w));
                uint4 u1 = make_uint4(PK(a2.x,a2.y), PK(a2.z,a2.w), PK(a3.x,a3.y), PK(a3.z,a3.w));
                uint4 u2 = make_uint4(PK(a4.x,a4.y), PK(a4.z,a4.w), PK(a5.x,a5.y), PK(a5.z,a5.w));
                D1m = MF(u0, fxf[0], D1m); D1m = MF(u1, fxf[1], D1m); D1m = MF(u2, fxf[2], D1m);
            }

            // ---- hop1 in-register: D (col a, rows h spread over lane halves)
            //      -> MFMA2 B-frags via half-wave exchange
            #pragma unroll
            for (int half = 0; half < 2; ++half) {
                const f32x16& D = half ? D1m : D0;
                unsigned int w0g[4], w1g[4];
                #pragma unroll
                for (int g = 0; g < 4; ++g) {
                    w0g[g] = PK(D[4*g],   D[4*g+1]);
                    w1g[g] = PK(D[4*g+2], D[4*g+3]);
                }
                #pragma unroll
                for (int ktl = 0; ktl < 2; ++ktl) {
                    const int gA = 2*ktl, gB = 2*ktl + 1;
                    unsigned int own0 = hf ? w0g[gB] : w0g[gA];
                    unsigned int own1 = hf ? w1g[gB] : w1g[gA];
                    unsigned int snd0 = hf ? w0g[gA] : w0g[gB];
                    unsigned int snd1 = hf ? w1g[gA] : w1g[gB];
                    unsigned int rcv0 = (unsigned int)__shfl_xor((int)snd0, 32, 64);
                    unsigned int rcv1 = (unsigned int)__shfl_xor((int)snd1, 32, 64);
                    uint4 frag;
                    frag.x = hf ? rcv0 : own0;
                    frag.y = hf ? rcv1 : own1;
                    frag.z = hf ? own0 : rcv0;
                    frag.w = hf ? own1 : rcv1;
                    D2 = MF(fyf[half*2 + ktl], frag, D2);
                }
            }

            // hop2: D2 (col a, rows b) -> a2t[b*22+a][t] f16
            if (al < 22) {
                #pragma unroll
                for (int q = 0; q < 16; ++q) {
                    int b = (q & 3) + 8*(q >> 2) + 4*hf;
                    unsigned short hv = __builtin_bit_cast(unsigned short, (_Float16)D2[q]);
                    a2t16[(b*22 + al)*34 + t] = hv;
                }
            }
        }
    }
    __syncthreads();

    // MFMA3: G[s][ba] = sum_t Ft[s][t] * A2t[ba][t]
    #pragma unroll 1
    for (int nt = wv; nt < 22; nt += 8) {
        int ba = nt*32 + al;
        f32x16 D3 = ZF();
        #pragma unroll
        for (int kt = 0; kt < 2; ++kt) {
            int base = ba*17 + kt*8 + 4*hf;
            uint4 bw;
            bw.x = a2t[base]; bw.y = a2t[base+1]; bw.z = a2t[base+2]; bw.w = a2t[base+3];
            D3 = MF(ftf[kt], bw, D3);
        }
        float* ob = out + obase + 176 + ba;
        #pragma unroll
        for (int q = 0; q < 16; ++q) {
            int s = (q & 3) + 8*(q >> 2) + 4*hf;
            if (s < XT) __builtin_nontemporal_store(gamma * D3[q], ob + s*OSLICE);
        }
    }
}

extern "C" void kernel_launch(void* const* d_in, const int* in_sizes, int n_in,
                              void* d_out, int out_size, void* d_ws, size_t ws_size,
                              hipStream_t stream) {
    const float* x   = (const float*)d_in[0];
    const float* dt  = (const float*)d_in[1];
    const float* dx  = (const float*)d_in[2];
    const float* dy  = (const float*)d_in[3];
    const float* ls2 = (const float*)d_in[4];
    const float* ldt = (const float*)d_in[5];
    const float* ld  = (const float*)d_in[6];
    const float* lg  = (const float*)d_in[7];
    float* out = (float*)d_out;
    unsigned int* ws = (unsigned int*)d_ws;   // 16 * 2304 * 4B = 147 KB

    prep_kernel<<<dim3(XN), dim3(96), 0, stream>>>(dt, dx, dy, ls2, ldt, ld, ws);
    glimpse_kernel<<<dim3(XN * XC), dim3(512), 0, stream>>>(x, ws, lg, out);
}